// Round 4
// baseline (220.883 us; speedup 1.0000x reference)
//
#include <hip/hip_runtime.h>
#include <math.h>

#define B_ 4
#define L_ 2048
#define S_ 2048
#define H_ 8
#define E_ 64
#define BH_ (B_*H_)
#define EPS 1e-6f

typedef __attribute__((ext_vector_type(8))) short short8;
typedef __attribute__((ext_vector_type(4))) float f32x4;

__device__ __forceinline__ unsigned short f2bf(float f) {
    unsigned int u = __float_as_uint(f);
    u = (u + 0x7fffu + ((u >> 16) & 1u)) >> 16;   // RNE
    return (unsigned short)u;
}

__device__ __forceinline__ float fast_tanh(float x) {
    float e = __expf(2.0f * x);
    return 1.0f - 2.0f / (e + 1.0f);
}

// XOR-swizzled LDS byte offset: rows of 128B, 16B chunks swizzled by row&7.
// Measured 0 LDS bank conflicts with this pattern (round 2).
__device__ __forceinline__ int swb(int row, int byteoff) {
    return row * 128 + ((((byteoff >> 4) ^ (row & 7)) << 4) | (byteoff & 15));
}

// ---------------------------------------------------------------------------
// K0 (fused preprocessing, partitioned grid):
//  blocks [0,2048):    q transform  -> qt  [B,H,L,E] bf16
//  blocks [2048,4096): k transform  -> kt  [B,H,S,E] bf16
//  blocks [4096,5120): v transpose  -> vt  [B,H,E,S] bf16
// transform: std over H axis (8 vals, ddof=1); tanh(x*dw/(std+eps))*dp
// ---------------------------------------------------------------------------
__global__ __launch_bounds__(256) void pre_kernel(
    const float* __restrict__ xq, const float* __restrict__ xk,
    const float* __restrict__ xv,
    unsigned short* __restrict__ qt, unsigned short* __restrict__ kt,
    unsigned short* __restrict__ vt,
    const float* __restrict__ dwp, const float* __restrict__ dpp)
{
    __shared__ float ls[64][65];
    int bx = blockIdx.x;
    if (bx < 4096) {
        const float* x = (bx < 2048) ? xq : xk;
        unsigned short* xt = (bx < 2048) ? qt : kt;
        int g = (bx & 2047) * 256 + threadIdx.x;   // over B*L*E = 524288
        int e = g & 63;
        int bl = g >> 6;
        int b = bl >> 11;                           // L_=2048
        int l = bl & 2047;
        size_t base = (size_t)bl * (H_ * E_) + e;
        float v[8], s = 0.f, q = 0.f;
#pragma unroll
        for (int h = 0; h < 8; ++h) {
            float t = x[base + h * E_];
            v[h] = t; s += t; q += t * t;
        }
        float mean = s * 0.125f;
        float var = (q - s * mean) * (1.f / 7.f);
        var = fmaxf(var, 0.f);
        float inv = 1.f / (sqrtf(var) + EPS);
        float wsc = dwp[0] * inv;
        float d = dpp[0];
#pragma unroll
        for (int h = 0; h < 8; ++h) {
            float t = fast_tanh(v[h] * wsc) * d;
            xt[((size_t)(b * H_ + h) * L_ + l) * E_ + e] = f2bf(t);
        }
    } else {
        // vtrans: [B,S,H,E] f32 -> [B,H,E,S] bf16, 64x64 tiles
        int t2 = bx - 4096;
        int s0 = (t2 & 31) * 64;
        int h = (t2 >> 5) & 7, b = t2 >> 8;
        int t = threadIdx.x;
#pragma unroll
        for (int i = 0; i < 4; ++i) {
            int idx = t + i * 256;
            int r = idx >> 4, c4 = (idx & 15) * 4;
            const float4 f = *(const float4*)&xv[((size_t)(b * S_ + s0 + r) * H_ + h) * E_ + c4];
            ls[r][c4] = f.x; ls[r][c4 + 1] = f.y; ls[r][c4 + 2] = f.z; ls[r][c4 + 3] = f.w;
        }
        __syncthreads();
        size_t ob = (size_t)(b * H_ + h) * E_ * S_ + s0;
#pragma unroll
        for (int i = 0; i < 16; ++i) {
            int idx = t + i * 256;
            int e = idx >> 6, s = idx & 63;
            vt[ob + (size_t)e * S_ + s] = f2bf(ls[s][e]);
        }
    }
}

// ---------------------------------------------------------------------------
// K0b: kt [B,H,S,E] bf16 -> ktT [B,H,E,S] bf16 (LDS-tiled transpose)
// ---------------------------------------------------------------------------
__global__ __launch_bounds__(256) void ktt_kernel(
    const unsigned short* __restrict__ kt, unsigned short* __restrict__ ktT)
{
    __shared__ unsigned short ls[64 * 72];   // pad to 72 u16/row: 2-way max
    int s0 = blockIdx.x * 64;
    int h = blockIdx.y, b = blockIdx.z;
    size_t bh = (size_t)(b * H_ + h);
    const unsigned short* src = kt + bh * S_ * E_ + (size_t)s0 * E_;
    int t = threadIdx.x;
#pragma unroll
    for (int i = 0; i < 2; ++i) {
        int u = t + i * 256;           // 512 short8 units
        int s = u >> 3, e8 = u & 7;
        *(short8*)&ls[s * 72 + e8 * 8] = *(const short8*)(src + u * 8);
    }
    __syncthreads();
    size_t ob = bh * E_ * S_ + s0;
#pragma unroll
    for (int i = 0; i < 16; ++i) {
        int idx = t + i * 256;
        int e = idx >> 6, s = idx & 63;
        ktT[ob + (size_t)e * S_ + s] = ls[s * 72 + e];
    }
}

// ---------------------------------------------------------------------------
// K1: per (b,h): G = Kt^T Kt (64x64, f32 acc -> bf16) and ksum[e] = sum_s kt
// One block per (b,h); waves split the S range.
// ---------------------------------------------------------------------------
__global__ __launch_bounds__(256) void gram_kernel(
    const unsigned short* __restrict__ ktT, unsigned short* __restrict__ Gb,
    float* __restrict__ ksum)
{
    __shared__ float gs[64 * 64];     // 16KB
    __shared__ float kss[64];
    int bh = blockIdx.x;
    const unsigned short* base = ktT + (size_t)bh * E_ * S_;
    int tid = threadIdx.x;
    int lane = tid & 63, w = tid >> 6;
    int m = lane & 15, quad = lane >> 4;

    f32x4 acc[4][4];
#pragma unroll
    for (int i = 0; i < 4; ++i)
#pragma unroll
        for (int j = 0; j < 4; ++j) acc[i][j] = (f32x4){0.f, 0.f, 0.f, 0.f};
    float ksp[4] = {0.f, 0.f, 0.f, 0.f};

    for (int c = w; c < S_ / 32; c += 4) {       // 16 chunks of 32 s per wave
        int s0 = c * 32;
        short8 af[4];
#pragma unroll
        for (int i = 0; i < 4; ++i) {
            af[i] = *(const short8*)(base + (size_t)(i * 16 + m) * S_ + s0 + quad * 8);
#pragma unroll
            for (int kk = 0; kk < 8; ++kk)
                ksp[i] += __uint_as_float(((unsigned int)(unsigned short)af[i][kk]) << 16);
        }
#pragma unroll
        for (int i = 0; i < 4; ++i)
#pragma unroll
            for (int j = 0; j < 4; ++j)
                acc[i][j] = __builtin_amdgcn_mfma_f32_16x16x32_bf16(af[i], af[j], acc[i][j], 0, 0, 0);
    }
    // reduce ksum partials over quads
#pragma unroll
    for (int i = 0; i < 4; ++i) {
        ksp[i] += __shfl_xor(ksp[i], 16);
        ksp[i] += __shfl_xor(ksp[i], 32);
    }
    // sequential cross-wave reduce in LDS
    for (int w2 = 0; w2 < 4; ++w2) {
        if (w == w2) {
#pragma unroll
            for (int i = 0; i < 4; ++i)
#pragma unroll
                for (int j = 0; j < 4; ++j)
#pragma unroll
                    for (int r = 0; r < 4; ++r) {
                        int idx = (i * 16 + quad * 4 + r) * 64 + j * 16 + m;
                        if (w2 == 0) gs[idx] = acc[i][j][r]; else gs[idx] += acc[i][j][r];
                    }
            if (lane < 16) {
#pragma unroll
                for (int i = 0; i < 4; ++i) {
                    int e = i * 16 + lane;
                    if (w2 == 0) kss[e] = ksp[i]; else kss[e] += ksp[i];
                }
            }
        }
        __syncthreads();
    }
#pragma unroll
    for (int ii = 0; ii < 16; ++ii) {
        int idx = tid + ii * 256;
        Gb[(size_t)bh * 4096 + idx] = f2bf(gs[idx]);
    }
    if (tid < 64) ksum[bh * 64 + tid] = kss[tid];
}

// ---------------------------------------------------------------------------
// K2: per q-row: T = Q*G (MFMA), sumsq = sum_e T.Q, rowsum = Q.ksum
//     alpha = 0.125/sqrt(var+eps), aw[row] = {alpha, alpha*mean}
// Block: 4 waves x 16 q-rows of one (b,h).
// ---------------------------------------------------------------------------
__global__ __launch_bounds__(256) void alpha_kernel(
    const unsigned short* __restrict__ qt, const unsigned short* __restrict__ Gb,
    const float* __restrict__ ksum, float2* __restrict__ aw)
{
    int tid = threadIdx.x;
    int lane = tid & 63, w = tid >> 6;
    int m = lane & 15, quad = lane >> 4;
    int l0 = blockIdx.x * 64 + w * 16;
    int h = blockIdx.y, b = blockIdx.z;
    size_t bh = (size_t)(b * H_ + h);
    const unsigned short* qtb = qt + bh * L_ * E_;
    const unsigned short* gb = Gb + bh * 4096;

    short8 qf[2];
#pragma unroll
    for (int c = 0; c < 2; ++c)
        qf[c] = *(const short8*)(qtb + (size_t)(l0 + m) * E_ + c * 32 + quad * 8);

    f32x4 accj[4];
#pragma unroll
    for (int j = 0; j < 4; ++j) {
        accj[j] = (f32x4){0.f, 0.f, 0.f, 0.f};
#pragma unroll
        for (int c = 0; c < 2; ++c) {
            short8 gf = *(const short8*)(gb + (size_t)(j * 16 + m) * 64 + c * 32 + quad * 8);
            accj[j] = __builtin_amdgcn_mfma_f32_16x16x32_bf16(qf[c], gf, accj[j], 0, 0, 0);
        }
    }
    // per lane: T[q=quad*4+r][e'=j*16+m]; load matching Q scalars + ksum
    float ps[4] = {0, 0, 0, 0}, pr[4] = {0, 0, 0, 0};
    float ksl[4];
#pragma unroll
    for (int j = 0; j < 4; ++j) ksl[j] = ksum[bh * 64 + j * 16 + m];
#pragma unroll
    for (int r = 0; r < 4; ++r) {
#pragma unroll
        for (int j = 0; j < 4; ++j) {
            float qv = __uint_as_float(
                ((unsigned int)qtb[(size_t)(l0 + quad * 4 + r) * E_ + j * 16 + m]) << 16);
            ps[r] = fmaf(accj[j][r], qv, ps[r]);
            pr[r] = fmaf(qv, ksl[j], pr[r]);
        }
    }
#pragma unroll
    for (int mask = 1; mask < 16; mask <<= 1)
#pragma unroll
        for (int r = 0; r < 4; ++r) {
            ps[r] += __shfl_xor(ps[r], mask);
            pr[r] += __shfl_xor(pr[r], mask);
        }
    if (m == 0) {
#pragma unroll
        for (int r = 0; r < 4; ++r) {
            float sum = pr[r], sq = ps[r];
            float mu = sum * (1.f / S_);
            float var = (sq - sum * mu) * (1.f / (S_ - 1));
            var = fmaxf(var, 0.f);
            float tau = sqrtf(var + EPS);
            float a = 0.125f / tau;
            aw[bh * L_ + l0 + quad * 4 + r] = make_float2(a, a * mu);
        }
    }
}

// ---------------------------------------------------------------------------
// K3: single-pass attention. Block = 2 waves x 32 q-rows = 64 rows of one
// (b,h). Per 64-S tile: stage K (dbuf, 1 barrier/iter, reg prefetch),
// QK = mfma(kf,qf) -> scores with 4 consecutive s per lane; p = exp(a*s-am)
// (mean-shifted, provably bounded); pack b64 -> wave-private pt (swizzled);
// PV = mfma(pf, vf) with V frags direct from global vt.
// ---------------------------------------------------------------------------
__global__ __launch_bounds__(128, 2) void attn_kernel(
    const unsigned short* __restrict__ qt,
    const unsigned short* __restrict__ kt,
    const unsigned short* __restrict__ vt,
    const float2* __restrict__ aw,
    float* __restrict__ out)
{
    __shared__ __align__(16) char lds[24576];
    const int tid = threadIdx.x;
    const int lane = tid & 63;
    const int w = tid >> 6;
    const int m = lane & 15;
    const int quad = lane >> 4;
    char* ptb = lds + 16384 + w * 4096;            // wave-private P: 32 x 128B

    const int l0 = blockIdx.x * 64;
    const int h = blockIdx.y, b = blockIdx.z;
    const size_t bh = (size_t)(b * H_ + h);
    const unsigned short* qtb = qt + bh * ((size_t)L_ * E_);
    const unsigned short* ktb = kt + bh * ((size_t)S_ * E_);
    const unsigned short* vtb = vt + bh * ((size_t)E_ * S_);

    // Q B-fragments (register-resident): lane m <-> q-row l0+w*32+g*16+m
    short8 qf[2][2];
#pragma unroll
    for (int g = 0; g < 2; ++g)
#pragma unroll
        for (int c = 0; c < 2; ++c)
            qf[g][c] = *(const short8*)(qtb + (size_t)(l0 + w * 32 + g * 16 + m) * E_ + c * 32 + quad * 8);

    float al[2], alm[2];
#pragma unroll
    for (int g = 0; g < 2; ++g) {
        float2 a2 = aw[bh * L_ + l0 + w * 32 + g * 16 + m];
        al[g] = a2.x; alm[g] = a2.y;
    }

    float dsum[2] = {0.f, 0.f};
    f32x4 oacc[2][4];
#pragma unroll
    for (int g = 0; g < 2; ++g)
#pragma unroll
        for (int et = 0; et < 4; ++et) oacc[g][et] = (f32x4){0.f, 0.f, 0.f, 0.f};

    // preload tile 0
    uint4 kr[4];
#pragma unroll
    for (int i = 0; i < 4; ++i) {
        int u = tid + i * 128;
        kr[i] = *(const uint4*)(ktb + (size_t)u * 8);
    }
#pragma unroll
    for (int i = 0; i < 4; ++i) {
        int u = tid + i * 128;
        *(uint4*)(lds + swb(u >> 3, (u & 7) * 16)) = kr[i];
    }
    __syncthreads();

    for (int st = 0; st < S_ / 64; ++st) {
        char* kcur = lds + (st & 1) * 8192;
        char* knxt = lds + ((st + 1) & 1) * 8192;
        // prefetch next K tile into registers
        if (st < S_ / 64 - 1) {
            const unsigned short* src = ktb + (size_t)(st + 1) * 64 * E_;
#pragma unroll
            for (int i = 0; i < 4; ++i) {
                int u = tid + i * 128;
                kr[i] = *(const uint4*)(src + (size_t)u * 8);
            }
        }
        // V B-fragments direct from global (VMEM pipe)
        short8 vf[2][4];
#pragma unroll
        for (int c = 0; c < 2; ++c)
#pragma unroll
            for (int et = 0; et < 4; ++et)
                vf[c][et] = *(const short8*)(vtb + (size_t)(et * 16 + m) * S_ + st * 64 + c * 32 + quad * 8);

        // QK: scores transposed, lane m <-> q-row, s in (nt,quad,r)
#pragma unroll
        for (int nt = 0; nt < 4; ++nt) {
            short8 kf0 = *(const short8*)(kcur + swb(nt * 16 + m, quad * 16));
            short8 kf1 = *(const short8*)(kcur + swb(nt * 16 + m, 64 + quad * 16));
#pragma unroll
            for (int g = 0; g < 2; ++g) {
                f32x4 acc = {0.f, 0.f, 0.f, 0.f};
                acc = __builtin_amdgcn_mfma_f32_16x16x32_bf16(kf0, qf[g][0], acc, 0, 0, 0);
                acc = __builtin_amdgcn_mfma_f32_16x16x32_bf16(kf1, qf[g][1], acc, 0, 0, 0);
                // p = exp(alpha*s - alpha*mu); truncate to bf16; dsum over
                // truncated values (consistent with stored P)
                unsigned int u0, u1, u2, u3;
                {
                    float p0 = __expf(fmaf(al[g], acc[0], -alm[g]));
                    float p1 = __expf(fmaf(al[g], acc[1], -alm[g]));
                    float p2 = __expf(fmaf(al[g], acc[2], -alm[g]));
                    float p3 = __expf(fmaf(al[g], acc[3], -alm[g]));
                    u0 = __float_as_uint(p0) & 0xffff0000u;
                    u1 = __float_as_uint(p1) & 0xffff0000u;
                    u2 = __float_as_uint(p2) & 0xffff0000u;
                    u3 = __float_as_uint(p3) & 0xffff0000u;
                    dsum[g] += __uint_as_float(u0) + __uint_as_float(u1)
                             + __uint_as_float(u2) + __uint_as_float(u3);
                }
                uint2 pk;
                pk.x = (u0 >> 16) | u1;
                pk.y = (u2 >> 16) | u3;
                *(uint2*)(ptb + swb(g * 16 + m, nt * 32 + quad * 8)) = pk;
            }
        }
        // PV (pt is wave-private: no barrier, lgkmcnt ordering suffices)
#pragma unroll
        for (int g = 0; g < 2; ++g) {
            short8 pf0 = *(const short8*)(ptb + swb(g * 16 + m, quad * 16));
            short8 pf1 = *(const short8*)(ptb + swb(g * 16 + m, 64 + quad * 16));
#pragma unroll
            for (int et = 0; et < 4; ++et) {
                oacc[g][et] = __builtin_amdgcn_mfma_f32_16x16x32_bf16(pf0, vf[0][et], oacc[g][et], 0, 0, 0);
                oacc[g][et] = __builtin_amdgcn_mfma_f32_16x16x32_bf16(pf1, vf[1][et], oacc[g][et], 0, 0, 0);
            }
        }
        // write prefetched tile to the other buffer; single barrier
        if (st < S_ / 64 - 1) {
#pragma unroll
            for (int i = 0; i < 4; ++i) {
                int u = tid + i * 128;
                *(uint4*)(knxt + swb(u >> 3, (u & 7) * 16)) = kr[i];
            }
        }
        __syncthreads();
    }

    // denominator: reduce over quads, then redistribute to C-layout rows
#pragma unroll
    for (int g = 0; g < 2; ++g) {
        dsum[g] += __shfl_xor(dsum[g], 16);
        dsum[g] += __shfl_xor(dsum[g], 32);
    }
#pragma unroll
    for (int g = 0; g < 2; ++g) {
#pragma unroll
        for (int r = 0; r < 4; ++r) {
            float dn = __shfl(dsum[g], quad * 4 + r);   // dsum for q-row g*16+quad*4+r
            float rd = 1.0f / dn;
            size_t row = (size_t)(b * L_ + l0 + w * 32 + g * 16 + quad * 4 + r);
#pragma unroll
            for (int et = 0; et < 4; ++et)
                out[(row * H_ + h) * E_ + et * 16 + m] = oacc[g][et][r] * rd;
        }
    }
}

extern "C" void kernel_launch(void* const* d_in, const int* in_sizes, int n_in,
                              void* d_out, int out_size, void* d_ws, size_t ws_size,
                              hipStream_t stream)
{
    const float* q = (const float*)d_in[0];
    const float* k = (const float*)d_in[1];
    const float* v = (const float*)d_in[2];
    // d_in[3] = attn_mask (unused)
    const float* dw = (const float*)d_in[4];
    const float* dp = (const float*)d_in[5];
    float* out = (float*)d_out;

    unsigned short* qt  = (unsigned short*)d_ws;                 // [B,H,L,E]
    unsigned short* kt  = qt  + (size_t)BH_ * L_ * E_;           // [B,H,S,E]
    unsigned short* ktT = kt  + (size_t)BH_ * S_ * E_;           // [B,H,E,S]
    unsigned short* vt  = ktT + (size_t)BH_ * E_ * S_;           // [B,H,E,S]
    unsigned short* Gb  = vt  + (size_t)BH_ * E_ * S_;           // [B,H,64,64]
    float* ksum = (float*)(Gb + (size_t)BH_ * 64 * 64);          // [B,H,64]
    float2* aw  = (float2*)(ksum + BH_ * 64);                    // [B,H,L]

    pre_kernel<<<5120, 256, 0, stream>>>(q, k, v, qt, kt, vt, dw, dp);
    dim3 tg(S_ / 64, H_, B_);
    ktt_kernel<<<tg, 256, 0, stream>>>(kt, ktT);
    gram_kernel<<<BH_, 256, 0, stream>>>(ktT, Gb, ksum);
    dim3 ag2(L_ / 64, H_, B_);
    alpha_kernel<<<ag2, 256, 0, stream>>>(qt, Gb, ksum, aw);
    attn_kernel<<<ag2, 128, 0, stream>>>(qt, kt, vt, aw, out);
}